// Round 5
// baseline (315.103 us; speedup 1.0000x reference)
//
#include <hip/hip_runtime.h>

#define SEQ 2048
#define DIM 1024

typedef __attribute__((ext_vector_type(8))) __bf16 bf16x8;
typedef __attribute__((ext_vector_type(4))) float f32x4;

typedef __attribute__((address_space(1))) unsigned char gu8_t;
typedef __attribute__((address_space(3))) unsigned char lu8_t;

__device__ __forceinline__ void async_copy16(const void* g, void* l) {
  __builtin_amdgcn_global_load_lds((gu8_t*)g, (lu8_t*)l, 16, 0, 0);
}

__device__ __forceinline__ ushort f2bf(float f) {
  union { float f; unsigned u; } v;
  v.f = f;
  unsigned r = v.u + 0x7FFFu + ((v.u >> 16) & 1u);
  return (ushort)(r >> 16);
}

__device__ __forceinline__ float bf2f_lo(unsigned u) {
  return __uint_as_float(u << 16);
}
__device__ __forceinline__ float bf2f_hi(unsigned u) {
  return __uint_as_float(u & 0xFFFF0000u);
}

__global__ void detect_dtype(const unsigned* __restrict__ words,
                             int* __restrict__ flag) {
  const int t = threadIdx.x;
  int hits = 0;
  for (int i = 0; i < 64; i++) {
    const unsigned w = words[t * 64 + i];
    const unsigned b = (w >> 8) & 0x7Fu;
    hits += (b >= 0x3Bu && b <= 0x42u) ? 1 : 0;
  }
#pragma unroll
  for (int o = 32; o > 0; o >>= 1) hits += __shfl_xor(hits, o, 64);
  if (t == 0) *flag = (hits > 2048) ? 1 : 0;
}

__global__ void convert_x(const void* __restrict__ in,
                          ushort* __restrict__ out,
                          const int* __restrict__ flag, int n8) {
  const int i = blockIdx.x * 256 + threadIdx.x;
  if (i >= n8) return;
  if (*flag) {
    reinterpret_cast<uint4*>(out)[i] = reinterpret_cast<const uint4*>(in)[i];
  } else {
    const float4* f = reinterpret_cast<const float4*>(in);
    const float4 a = f[2 * i], b = f[2 * i + 1];
    ushort4 lo, hi;
    lo.x = f2bf(a.x); lo.y = f2bf(a.y); lo.z = f2bf(a.z); lo.w = f2bf(a.w);
    hi.x = f2bf(b.x); hi.y = f2bf(b.y); hi.z = f2bf(b.z); hi.w = f2bf(b.w);
    reinterpret_cast<ushort4*>(out)[2 * i] = lo;
    reinterpret_cast<ushort4*>(out)[2 * i + 1] = hi;
  }
}

__global__ void transpose_w(const void* __restrict__ w0,
                            const void* __restrict__ w1,
                            const void* __restrict__ w2,
                            ushort* __restrict__ out,
                            const int* __restrict__ flag) {
  __shared__ ushort tile[64][68];
  const int z = blockIdx.z;
  const void* in = (z == 0) ? w0 : (z == 1) ? w1 : w2;
  ushort* op = out + (size_t)z * 1024 * 1024;
  const int c0 = blockIdx.x * 64, r0 = blockIdx.y * 64;
  const int t = threadIdx.x;
  if (*flag) {
    const ushort* ip = (const ushort*)in;
#pragma unroll
    for (int i = 0; i < 4; i++) {
      const int lin = i * 256 + t;
      const int r = lin >> 4, c4 = (lin & 15) << 2;
      const ushort4 v = *reinterpret_cast<const ushort4*>(
          ip + (size_t)(r0 + r) * 1024 + c0 + c4);
      tile[r][c4 + 0] = v.x; tile[r][c4 + 1] = v.y;
      tile[r][c4 + 2] = v.z; tile[r][c4 + 3] = v.w;
    }
  } else {
    const float* ip = (const float*)in;
#pragma unroll
    for (int i = 0; i < 4; i++) {
      const int lin = i * 256 + t;
      const int r = lin >> 4, c4 = (lin & 15) << 2;
      const float4 v = *reinterpret_cast<const float4*>(
          ip + (size_t)(r0 + r) * 1024 + c0 + c4);
      tile[r][c4 + 0] = f2bf(v.x); tile[r][c4 + 1] = f2bf(v.y);
      tile[r][c4 + 2] = f2bf(v.z); tile[r][c4 + 3] = f2bf(v.w);
    }
  }
  __syncthreads();
#pragma unroll
  for (int i = 0; i < 4; i++) {
    const int lin = i * 256 + t;
    const int c = lin >> 4, r4 = (lin & 15) << 2;
    ushort4 v;
    v.x = tile[r4 + 0][c]; v.y = tile[r4 + 1][c];
    v.z = tile[r4 + 2][c]; v.w = tile[r4 + 3][c];
    *reinterpret_cast<ushort4*>(op + (size_t)(c0 + c) * 1024 + r0 + r4) = v;
  }
}

__global__ void transpose_bf16(const ushort* __restrict__ in,
                               ushort* __restrict__ out, int R, int C,
                               long inZ, long outZ) {
  __shared__ ushort tile[64][68];
  const ushort* ip = in + (size_t)blockIdx.z * inZ;
  ushort* op = out + (size_t)blockIdx.z * outZ;
  const int c0 = blockIdx.x * 64, r0 = blockIdx.y * 64;
  const int t = threadIdx.x;
#pragma unroll
  for (int i = 0; i < 4; i++) {
    const int lin = i * 256 + t;
    const int r = lin >> 4, c4 = (lin & 15) << 2;
    const ushort4 v =
        *reinterpret_cast<const ushort4*>(ip + (size_t)(r0 + r) * C + c0 + c4);
    tile[r][c4 + 0] = v.x; tile[r][c4 + 1] = v.y;
    tile[r][c4 + 2] = v.z; tile[r][c4 + 3] = v.w;
  }
  __syncthreads();
#pragma unroll
  for (int i = 0; i < 4; i++) {
    const int lin = i * 256 + t;
    const int c = lin >> 4, r4 = (lin & 15) << 2;
    ushort4 v;
    v.x = tile[r4 + 0][c]; v.y = tile[r4 + 1][c];
    v.z = tile[r4 + 2][c]; v.w = tile[r4 + 3][c];
    *reinterpret_cast<ushort4*>(op + (size_t)(c0 + c) * R + r0 + r4) = v;
  }
}

// XCD-aware swizzle GEMM (verified r4: FETCH 135->41MB). C=A*Bt^T, 128x128.
// outKind: 0 fp32, 1 bf16, 2 flag-dependent.
__global__ __launch_bounds__(256, 4) void gemm_bt(
    const ushort* __restrict__ A, const ushort* __restrict__ Bt,
    void* __restrict__ Cv, const int* __restrict__ flag, int M, int N, int K,
    long aZ, long bZ, long cZ, int zBase, float scale0, float scale1,
    int triSkip, int outKind) {
  __shared__ ushort lA[128 * 32];
  __shared__ ushort lB[128 * 32];

  const int nT = gridDim.x;
  const int id = blockIdx.y * nT + blockIdx.x;
  const int xcd = id & 7;
  const int loc = id >> 3;
  const int n0 = (loc % nT) * 128;
  const int m0 = (xcd + ((loc / nT) << 3)) * 128;
  if (triSkip && n0 > m0 + 127) return;

  const ushort* Ab = A + (size_t)blockIdx.z * aZ;
  const ushort* Bb = Bt + (size_t)blockIdx.z * bZ;

  const int t = threadIdx.x;
  const int lane = t & 63;
  const int w = t >> 6;
  const int wm = (w >> 1) * 64;
  const int wn = (w & 1) * 64;
  const int quad = lane >> 4;
  const int l15 = lane & 15;

  f32x4 acc[4][4] = {};

  const int idx0 = t;
  const int idx1 = t + 256;
  const int rowA0 = idx0 >> 2, colA0 = (idx0 & 3) << 3;
  const int rowA1 = idx1 >> 2, colA1 = (idx1 & 3) << 3;

  for (int k0 = 0; k0 < K; k0 += 32) {
    __syncthreads();
    async_copy16(Ab + (size_t)(m0 + rowA0) * K + k0 + colA0, lA + idx0 * 8);
    async_copy16(Ab + (size_t)(m0 + rowA1) * K + k0 + colA1, lA + idx1 * 8);
    async_copy16(Bb + (size_t)(n0 + rowA0) * K + k0 + colA0, lB + idx0 * 8);
    async_copy16(Bb + (size_t)(n0 + rowA1) * K + k0 + colA1, lB + idx1 * 8);
    __syncthreads();

    bf16x8 af[4], bfr[4];
#pragma unroll
    for (int mi = 0; mi < 4; mi++)
      af[mi] = *(const bf16x8*)(lA + (wm + mi * 16 + l15) * 32 + quad * 8);
#pragma unroll
    for (int ni = 0; ni < 4; ni++)
      bfr[ni] = *(const bf16x8*)(lB + (wn + ni * 16 + l15) * 32 + quad * 8);
#pragma unroll
    for (int mi = 0; mi < 4; mi++)
#pragma unroll
      for (int ni = 0; ni < 4; ni++)
        acc[mi][ni] = __builtin_amdgcn_mfma_f32_16x16x32_bf16(
            af[mi], bfr[ni], acc[mi][ni], 0, 0, 0);
  }

  const float scale = (blockIdx.z == 0 && zBase == 0) ? scale0 : scale1;
  const bool storeBf = (outKind == 1) || (outKind == 2 && *flag != 0);
  const size_t zc = (size_t)(zBase + blockIdx.z) * cZ;
#pragma unroll
  for (int mi = 0; mi < 4; mi++)
#pragma unroll
    for (int ni = 0; ni < 4; ni++)
#pragma unroll
      for (int r = 0; r < 4; r++) {
        const int row = m0 + wm + mi * 16 + quad * 4 + r;  // col=lane&15,
        const int col = n0 + wn + ni * 16 + l15;           // row=quad*4+r
        const float vv = acc[mi][ni][r] * scale;
        if (storeBf) {
          ushort* C = (ushort*)Cv + zc;
          C[(size_t)row * N + col] = f2bf(vv);
        } else {
          float* C = (float*)Cv + zc;
          C[(size_t)row * N + col] = vv;
        }
      }
}

// Per-row softmax stats over bf16 logits: stats[row] = (max, 1/sum_exp).
// Thread t handles elements {it*512 + 2t, +1}, it=0..3 (uint loads).
__global__ void softmax_stats(const ushort* __restrict__ Sc,
                              float2* __restrict__ stats) {
  const int rid = blockIdx.x;
  const int i = rid & (SEQ - 1);
  const ushort* row = Sc + (size_t)rid * SEQ;
  const int t = threadIdx.x;
  __shared__ float red[4];

  float r[8];
  float mx = -3.0e38f;
#pragma unroll
  for (int it = 0; it < 4; it++) {
    const int j = it * 512 + 2 * t;
    unsigned u = 0;
    if (j <= i) u = *reinterpret_cast<const unsigned*>(row + j);
    r[2 * it] = (j <= i) ? bf2f_lo(u) : -3.0e38f;
    r[2 * it + 1] = (j + 1 <= i) ? bf2f_hi(u) : -3.0e38f;
    mx = fmaxf(mx, fmaxf(r[2 * it], r[2 * it + 1]));
  }
#pragma unroll
  for (int o = 32; o > 0; o >>= 1) mx = fmaxf(mx, __shfl_xor(mx, o, 64));
  if ((t & 63) == 0) red[t >> 6] = mx;
  __syncthreads();
  mx = fmaxf(fmaxf(red[0], red[1]), fmaxf(red[2], red[3]));
  __syncthreads();

  float sum = 0.0f;
#pragma unroll
  for (int it = 0; it < 8; it++) sum += __expf(r[it] - mx);
#pragma unroll
  for (int o = 32; o > 0; o >>= 1) sum += __shfl_xor(sum, o, 64);
  if ((t & 63) == 0) red[t >> 6] = sum;
  __syncthreads();
  sum = red[0] + red[1] + red[2] + red[3];
  if (t == 0) stats[rid] = make_float2(mx, 1.0f / sum);
}

// PV GEMM with fused softmax normalization: A = bf16 logits; staging applies
// p = exp(s - m_row) * inv_row with causal mask, packs bf16 -> LDS. B = Vt.
// K-loop limited to m0+128 (causal). Out: flag-dependent dtype.
__global__ __launch_bounds__(256, 4) void gemm_pv(
    const ushort* __restrict__ Sc, const ushort* __restrict__ Vt,
    const float2* __restrict__ stats, void* __restrict__ Cv,
    const int* __restrict__ flag, long cZ) {
  __shared__ ushort lA[128 * 32];
  __shared__ ushort lB[128 * 32];
  __shared__ float2 st_s[128];

  const int N = DIM, K = SEQ;
  const int nT = gridDim.x;  // 8
  const int id = blockIdx.y * nT + blockIdx.x;
  const int xcd = id & 7;
  const int loc = id >> 3;
  const int n0 = (loc % nT) * 128;
  const int m0 = (xcd + ((loc / nT) << 3)) * 128;

  const ushort* Ab = Sc + (size_t)blockIdx.z * SEQ * SEQ;
  const ushort* Bb = Vt + (size_t)blockIdx.z * (size_t)DIM * SEQ;

  const int t = threadIdx.x;
  const int lane = t & 63;
  const int w = t >> 6;
  const int wm = (w >> 1) * 64;
  const int wn = (w & 1) * 64;
  const int quad = lane >> 4;
  const int l15 = lane & 15;

  if (t < 128) st_s[t] = stats[(size_t)blockIdx.z * SEQ + m0 + t];

  f32x4 acc[4][4] = {};

  const int kEnd = m0 + 128;  // causal: cols <= q < m0+128

  const int idx0 = t;
  const int idx1 = t + 256;
  const int rowA0 = idx0 >> 2, colA0 = (idx0 & 3) << 3;
  const int rowA1 = idx1 >> 2, colA1 = (idx1 & 3) << 3;

  for (int k0 = 0; k0 < kEnd; k0 += 32) {
    __syncthreads();  // also covers st_s preload on first iter
    async_copy16(Bb + (size_t)(n0 + rowA0) * K + k0 + colA0, lB + idx0 * 8);
    async_copy16(Bb + (size_t)(n0 + rowA1) * K + k0 + colA1, lB + idx1 * 8);
#pragma unroll
    for (int c = 0; c < 2; c++) {
      const int idx = (c == 0) ? idx0 : idx1;
      const int row = (c == 0) ? rowA0 : rowA1;
      const int col = (c == 0) ? colA0 : colA1;
      const int q = m0 + row;
      const float2 st = st_s[row];
      const uint4 s4 = *reinterpret_cast<const uint4*>(
          Ab + (size_t)q * K + k0 + col);
      const unsigned words[4] = {s4.x, s4.y, s4.z, s4.w};
      uint4 o4;
      unsigned ow[4];
#pragma unroll
      for (int jj = 0; jj < 4; jj++) {
        const int kb = k0 + col + 2 * jj;
        const float p0 =
            (kb <= q) ? __expf(bf2f_lo(words[jj]) - st.x) * st.y : 0.0f;
        const float p1 =
            (kb + 1 <= q) ? __expf(bf2f_hi(words[jj]) - st.x) * st.y : 0.0f;
        ow[jj] = (unsigned)f2bf(p0) | ((unsigned)f2bf(p1) << 16);
      }
      o4.x = ow[0]; o4.y = ow[1]; o4.z = ow[2]; o4.w = ow[3];
      *reinterpret_cast<uint4*>(lA + idx * 8) = o4;
    }
    __syncthreads();

    bf16x8 af[4], bfr[4];
#pragma unroll
    for (int mi = 0; mi < 4; mi++)
      af[mi] = *(const bf16x8*)(lA + (wm + mi * 16 + l15) * 32 + quad * 8);
#pragma unroll
    for (int ni = 0; ni < 4; ni++)
      bfr[ni] = *(const bf16x8*)(lB + (wn + ni * 16 + l15) * 32 + quad * 8);
#pragma unroll
    for (int mi = 0; mi < 4; mi++)
#pragma unroll
      for (int ni = 0; ni < 4; ni++)
        acc[mi][ni] = __builtin_amdgcn_mfma_f32_16x16x32_bf16(
            af[mi], bfr[ni], acc[mi][ni], 0, 0, 0);
  }

  const bool storeBf = (*flag != 0);
  const size_t zc = (size_t)blockIdx.z * cZ;
#pragma unroll
  for (int mi = 0; mi < 4; mi++)
#pragma unroll
    for (int ni = 0; ni < 4; ni++)
#pragma unroll
      for (int r = 0; r < 4; r++) {
        const int row = m0 + wm + mi * 16 + quad * 4 + r;
        const int col = n0 + wn + ni * 16 + l15;
        const float vv = acc[mi][ni][r];
        if (storeBf) {
          ushort* C = (ushort*)Cv + zc;
          C[(size_t)row * N + col] = f2bf(vv);
        } else {
          float* C = (float*)Cv + zc;
          C[(size_t)row * N + col] = vv;
        }
      }
}

// Workspace (MB): 0 flag | 1 wt(6) | 7 xb(16) | 23 q | 39 k | 55 v |
// 71 vt(16) | 87 sc bf16(32) | 119 stats(64KB)
extern "C" void kernel_launch(void* const* d_in, const int* in_sizes, int n_in,
                              void* d_out, int out_size, void* d_ws,
                              size_t ws_size, hipStream_t stream) {
  char* ws = (char*)d_ws;
  const size_t MB = 1024 * 1024;
  int* flag = (int*)ws;
  ushort* wt = (ushort*)(ws + 1 * MB);
  ushort* xb = (ushort*)(ws + 7 * MB);
  ushort* q = (ushort*)(ws + 23 * MB);
  ushort* kk = (ushort*)(ws + 39 * MB);
  ushort* v = (ushort*)(ws + 55 * MB);
  ushort* vt = (ushort*)(ws + 71 * MB);
  ushort* sc = (ushort*)(ws + 87 * MB);
  float2* stats = (float2*)(ws + 119 * MB);
  (void)kk;

  detect_dtype<<<dim3(1), 64, 0, stream>>>((const unsigned*)d_in[0], flag);

  convert_x<<<dim3(4096), 256, 0, stream>>>(d_in[0], xb, flag,
                                            (8192 * 1024) / 8);

  transpose_w<<<dim3(16, 16, 3), 256, 0, stream>>>(d_in[1], d_in[2], d_in[3],
                                                   wt, flag);

  // QKV projections: z=0 -> Q (scaled 1/sqrt(1024)=1/32), z=1 -> K, z=2 -> V
  gemm_bt<<<dim3(8, 64, 3), 256, 0, stream>>>(
      xb, wt, (void*)q, flag, 8192, 1024, 1024, 0L, (long)1024 * 1024,
      (long)8192 * 1024, 0, 0.03125f, 1.0f, 0, 1);

  transpose_bf16<<<dim3(16, 32, 4), 256, 0, stream>>>(
      v, vt, 2048, 1024, (long)SEQ * DIM, (long)DIM * SEQ);

  // scores S = Q*K^T -> bf16 logits, upper-triangular blocks skipped
  gemm_bt<<<dim3(16, 16, 4), 256, 0, stream>>>(
      q, kk, (void*)sc, flag, 2048, 2048, 1024, (long)SEQ * DIM,
      (long)SEQ * DIM, (long)SEQ * SEQ, 0, 1.0f, 1.0f, 1, 1);

  // per-row (max, 1/sum)
  softmax_stats<<<dim3(4 * SEQ), 256, 0, stream>>>(sc, stats);

  // out = softmax(S) @ V with exp fused into staging
  gemm_pv<<<dim3(8, 16, 4), 256, 0, stream>>>(sc, vt, stats, d_out, flag,
                                              (long)SEQ * DIM);
}

// Round 6
// 275.345 us; speedup vs baseline: 1.1444x; 1.1444x over previous
//
#include <hip/hip_runtime.h>

#define SEQ 2048
#define DIM 1024

typedef __attribute__((ext_vector_type(8))) __bf16 bf16x8;
typedef __attribute__((ext_vector_type(4))) float f32x4;

typedef __attribute__((address_space(1))) unsigned char gu8_t;
typedef __attribute__((address_space(3))) unsigned char lu8_t;

__device__ __forceinline__ void async_copy16(const void* g, void* l) {
  __builtin_amdgcn_global_load_lds((gu8_t*)g, (lu8_t*)l, 16, 0, 0);
}

__device__ __forceinline__ ushort f2bf(float f) {
  union { float f; unsigned u; } v;
  v.f = f;
  unsigned r = v.u + 0x7FFFu + ((v.u >> 16) & 1u);
  return (ushort)(r >> 16);
}

__device__ __forceinline__ float bf2f_lo(unsigned u) {
  return __uint_as_float(u << 16);
}
__device__ __forceinline__ float bf2f_hi(unsigned u) {
  return __uint_as_float(u & 0xFFFF0000u);
}

__global__ void detect_dtype(const unsigned* __restrict__ words,
                             int* __restrict__ flag) {
  const int t = threadIdx.x;
  int hits = 0;
  for (int i = 0; i < 64; i++) {
    const unsigned w = words[t * 64 + i];
    const unsigned b = (w >> 8) & 0x7Fu;
    hits += (b >= 0x3Bu && b <= 0x42u) ? 1 : 0;
  }
#pragma unroll
  for (int o = 32; o > 0; o >>= 1) hits += __shfl_xor(hits, o, 64);
  if (t == 0) *flag = (hits > 2048) ? 1 : 0;
}

__global__ void convert_x(const void* __restrict__ in,
                          ushort* __restrict__ out,
                          const int* __restrict__ flag, int n8) {
  const int i = blockIdx.x * 256 + threadIdx.x;
  if (i >= n8) return;
  if (*flag) {
    reinterpret_cast<uint4*>(out)[i] = reinterpret_cast<const uint4*>(in)[i];
  } else {
    const float4* f = reinterpret_cast<const float4*>(in);
    const float4 a = f[2 * i], b = f[2 * i + 1];
    ushort4 lo, hi;
    lo.x = f2bf(a.x); lo.y = f2bf(a.y); lo.z = f2bf(a.z); lo.w = f2bf(a.w);
    hi.x = f2bf(b.x); hi.y = f2bf(b.y); hi.z = f2bf(b.z); hi.w = f2bf(b.w);
    reinterpret_cast<ushort4*>(out)[2 * i] = lo;
    reinterpret_cast<ushort4*>(out)[2 * i + 1] = hi;
  }
}

__global__ void transpose_w(const void* __restrict__ w0,
                            const void* __restrict__ w1,
                            const void* __restrict__ w2,
                            ushort* __restrict__ out,
                            const int* __restrict__ flag) {
  __shared__ ushort tile[64][68];
  const int z = blockIdx.z;
  const void* in = (z == 0) ? w0 : (z == 1) ? w1 : w2;
  ushort* op = out + (size_t)z * 1024 * 1024;
  const int c0 = blockIdx.x * 64, r0 = blockIdx.y * 64;
  const int t = threadIdx.x;
  if (*flag) {
    const ushort* ip = (const ushort*)in;
#pragma unroll
    for (int i = 0; i < 4; i++) {
      const int lin = i * 256 + t;
      const int r = lin >> 4, c4 = (lin & 15) << 2;
      const ushort4 v = *reinterpret_cast<const ushort4*>(
          ip + (size_t)(r0 + r) * 1024 + c0 + c4);
      tile[r][c4 + 0] = v.x; tile[r][c4 + 1] = v.y;
      tile[r][c4 + 2] = v.z; tile[r][c4 + 3] = v.w;
    }
  } else {
    const float* ip = (const float*)in;
#pragma unroll
    for (int i = 0; i < 4; i++) {
      const int lin = i * 256 + t;
      const int r = lin >> 4, c4 = (lin & 15) << 2;
      const float4 v = *reinterpret_cast<const float4*>(
          ip + (size_t)(r0 + r) * 1024 + c0 + c4);
      tile[r][c4 + 0] = f2bf(v.x); tile[r][c4 + 1] = f2bf(v.y);
      tile[r][c4 + 2] = f2bf(v.z); tile[r][c4 + 3] = f2bf(v.w);
    }
  }
  __syncthreads();
#pragma unroll
  for (int i = 0; i < 4; i++) {
    const int lin = i * 256 + t;
    const int c = lin >> 4, r4 = (lin & 15) << 2;
    ushort4 v;
    v.x = tile[r4 + 0][c]; v.y = tile[r4 + 1][c];
    v.z = tile[r4 + 2][c]; v.w = tile[r4 + 3][c];
    *reinterpret_cast<ushort4*>(op + (size_t)(c0 + c) * 1024 + r0 + r4) = v;
  }
}

__global__ void transpose_bf16(const ushort* __restrict__ in,
                               ushort* __restrict__ out, int R, int C,
                               long inZ, long outZ) {
  __shared__ ushort tile[64][68];
  const ushort* ip = in + (size_t)blockIdx.z * inZ;
  ushort* op = out + (size_t)blockIdx.z * outZ;
  const int c0 = blockIdx.x * 64, r0 = blockIdx.y * 64;
  const int t = threadIdx.x;
#pragma unroll
  for (int i = 0; i < 4; i++) {
    const int lin = i * 256 + t;
    const int r = lin >> 4, c4 = (lin & 15) << 2;
    const ushort4 v =
        *reinterpret_cast<const ushort4*>(ip + (size_t)(r0 + r) * C + c0 + c4);
    tile[r][c4 + 0] = v.x; tile[r][c4 + 1] = v.y;
    tile[r][c4 + 2] = v.z; tile[r][c4 + 3] = v.w;
  }
  __syncthreads();
#pragma unroll
  for (int i = 0; i < 4; i++) {
    const int lin = i * 256 + t;
    const int c = lin >> 4, r4 = (lin & 15) << 2;
    ushort4 v;
    v.x = tile[r4 + 0][c]; v.y = tile[r4 + 1][c];
    v.z = tile[r4 + 2][c]; v.w = tile[r4 + 3][c];
    *reinterpret_cast<ushort4*>(op + (size_t)(c0 + c) * R + r0 + r4) = v;
  }
}

// XCD-aware swizzle GEMM (r4: FETCH 135->41MB). C=A*Bt^T, 128x128 tile.
// causalBal=1 (needs gridDim.y==16): XCD gets m-tile pair {xcd, 15-xcd} ->
// constant causal work per XCD. Else m-tiles striped by xcd (r4 mapping).
// outKind: 0 fp32, 1 bf16, 2 flag-dependent.
__global__ __launch_bounds__(256, 4) void gemm_bt(
    const ushort* __restrict__ A, const ushort* __restrict__ Bt,
    void* __restrict__ Cv, const int* __restrict__ flag, int M, int N, int K,
    long aZ, long bZ, long cZ, int zBase, float scale0, float scale1,
    int triSkip, int causalK, int causalBal, int outKind) {
  __shared__ ushort lA[128 * 32];
  __shared__ ushort lB[128 * 32];

  const int nT = gridDim.x;
  const int id = blockIdx.y * nT + blockIdx.x;
  const int xcd = id & 7;
  const int loc = id >> 3;
  const int nt = loc % nT;
  const int mt = causalBal ? ((loc / nT == 0) ? xcd : ((int)gridDim.y - 1 - xcd))
                           : (xcd + ((loc / nT) << 3));
  const int n0 = nt * 128;
  const int m0 = mt * 128;
  if (triSkip && n0 > m0 + 127) return;

  const ushort* Ab = A + (size_t)blockIdx.z * aZ;
  const ushort* Bb = Bt + (size_t)blockIdx.z * bZ;

  const int t = threadIdx.x;
  const int lane = t & 63;
  const int w = t >> 6;
  const int wm = (w >> 1) * 64;
  const int wn = (w & 1) * 64;
  const int quad = lane >> 4;
  const int l15 = lane & 15;

  f32x4 acc[4][4] = {};

  const int kEnd = causalK ? ((m0 + 128 < K) ? (m0 + 128) : K) : K;

  const int idx0 = t;
  const int idx1 = t + 256;
  const int rowA0 = idx0 >> 2, colA0 = (idx0 & 3) << 3;
  const int rowA1 = idx1 >> 2, colA1 = (idx1 & 3) << 3;

  for (int k0 = 0; k0 < kEnd; k0 += 32) {
    __syncthreads();
    async_copy16(Ab + (size_t)(m0 + rowA0) * K + k0 + colA0, lA + idx0 * 8);
    async_copy16(Ab + (size_t)(m0 + rowA1) * K + k0 + colA1, lA + idx1 * 8);
    async_copy16(Bb + (size_t)(n0 + rowA0) * K + k0 + colA0, lB + idx0 * 8);
    async_copy16(Bb + (size_t)(n0 + rowA1) * K + k0 + colA1, lB + idx1 * 8);
    __syncthreads();

    bf16x8 af[4], bfr[4];
#pragma unroll
    for (int mi = 0; mi < 4; mi++)
      af[mi] = *(const bf16x8*)(lA + (wm + mi * 16 + l15) * 32 + quad * 8);
#pragma unroll
    for (int ni = 0; ni < 4; ni++)
      bfr[ni] = *(const bf16x8*)(lB + (wn + ni * 16 + l15) * 32 + quad * 8);
#pragma unroll
    for (int mi = 0; mi < 4; mi++)
#pragma unroll
      for (int ni = 0; ni < 4; ni++)
        acc[mi][ni] = __builtin_amdgcn_mfma_f32_16x16x32_bf16(
            af[mi], bfr[ni], acc[mi][ni], 0, 0, 0);
  }

  const float scale = (blockIdx.z == 0 && zBase == 0) ? scale0 : scale1;
  const bool storeBf = (outKind == 1) || (outKind == 2 && *flag != 0);
  const size_t zc = (size_t)(zBase + blockIdx.z) * cZ;
#pragma unroll
  for (int mi = 0; mi < 4; mi++)
#pragma unroll
    for (int ni = 0; ni < 4; ni++)
#pragma unroll
      for (int r = 0; r < 4; r++) {
        const int row = m0 + wm + mi * 16 + quad * 4 + r;  // col=lane&15,
        const int col = n0 + wn + ni * 16 + l15;           // row=quad*4+r
        const float vv = acc[mi][ni][r] * scale;
        if (storeBf) {
          ushort* C = (ushort*)Cv + zc;
          C[(size_t)row * N + col] = f2bf(vv);
        } else {
          float* C = (float*)Cv + zc;
          C[(size_t)row * N + col] = vv;
        }
      }
}

// Causal softmax over bf16 logit rows -> bf16 P. Row cached in 8 regs:
// one 16B-granule read pass, one expf pass, packed uint stores.
__global__ void softmax_p(const ushort* __restrict__ Sc,
                          ushort* __restrict__ P) {
  const int rid = blockIdx.x;
  const int i = rid & (SEQ - 1);
  const ushort* row = Sc + (size_t)rid * SEQ;
  ushort* prow = P + (size_t)rid * SEQ;
  const int t = threadIdx.x;
  __shared__ float red[4];

  float r[8];
  float mx = -3.0e38f;
#pragma unroll
  for (int it = 0; it < 4; it++) {
    const int j = it * 512 + 2 * t;
    const unsigned u = *reinterpret_cast<const unsigned*>(row + j);
    r[2 * it] = (j <= i) ? bf2f_lo(u) : -3.0e38f;
    r[2 * it + 1] = (j + 1 <= i) ? bf2f_hi(u) : -3.0e38f;
    mx = fmaxf(mx, fmaxf(r[2 * it], r[2 * it + 1]));
  }
#pragma unroll
  for (int o = 32; o > 0; o >>= 1) mx = fmaxf(mx, __shfl_xor(mx, o, 64));
  if ((t & 63) == 0) red[t >> 6] = mx;
  __syncthreads();
  mx = fmaxf(fmaxf(red[0], red[1]), fmaxf(red[2], red[3]));
  __syncthreads();

  float sum = 0.0f;
#pragma unroll
  for (int it = 0; it < 8; it++) {
    r[it] = __expf(r[it] - mx);  // masked lanes: exp(-huge) == 0
    sum += r[it];
  }
#pragma unroll
  for (int o = 32; o > 0; o >>= 1) sum += __shfl_xor(sum, o, 64);
  if ((t & 63) == 0) red[t >> 6] = sum;
  __syncthreads();
  sum = red[0] + red[1] + red[2] + red[3];
  const float inv = 1.0f / sum;

#pragma unroll
  for (int it = 0; it < 4; it++) {
    const int j = it * 512 + 2 * t;
    const unsigned w = (unsigned)f2bf(r[2 * it] * inv) |
                       ((unsigned)f2bf(r[2 * it + 1] * inv) << 16);
    *reinterpret_cast<unsigned*>(prow + j) = w;
  }
}

// Workspace (MB): 0 flag | 1 wt(6) | 7 xb(16) | 23 q | 39 k | 55 v |
// 71 vt(16) | 87 sc bf16(32) | 119 p bf16(32)  => 151 MB total
extern "C" void kernel_launch(void* const* d_in, const int* in_sizes, int n_in,
                              void* d_out, int out_size, void* d_ws,
                              size_t ws_size, hipStream_t stream) {
  char* ws = (char*)d_ws;
  const size_t MB = 1024 * 1024;
  int* flag = (int*)ws;
  ushort* wt = (ushort*)(ws + 1 * MB);
  ushort* xb = (ushort*)(ws + 7 * MB);
  ushort* q = (ushort*)(ws + 23 * MB);
  ushort* kk = (ushort*)(ws + 39 * MB);
  ushort* v = (ushort*)(ws + 55 * MB);
  ushort* vt = (ushort*)(ws + 71 * MB);
  ushort* sc = (ushort*)(ws + 87 * MB);
  ushort* p = (ushort*)(ws + 119 * MB);
  (void)kk;

  detect_dtype<<<dim3(1), 64, 0, stream>>>((const unsigned*)d_in[0], flag);

  convert_x<<<dim3(4096), 256, 0, stream>>>(d_in[0], xb, flag,
                                            (8192 * 1024) / 8);

  transpose_w<<<dim3(16, 16, 3), 256, 0, stream>>>(d_in[1], d_in[2], d_in[3],
                                                   wt, flag);

  // QKV projections: z=0 -> Q (scaled 1/sqrt(1024)=1/32), z=1 -> K, z=2 -> V
  gemm_bt<<<dim3(8, 64, 3), 256, 0, stream>>>(
      xb, wt, (void*)q, flag, 8192, 1024, 1024, 0L, (long)1024 * 1024,
      (long)8192 * 1024, 0, 0.03125f, 1.0f, 0, 0, 0, 1);

  transpose_bf16<<<dim3(16, 32, 4), 256, 0, stream>>>(
      v, vt, 2048, 1024, (long)SEQ * DIM, (long)DIM * SEQ);

  // scores S = Q*K^T -> bf16 logits; balanced causal swizzle + triSkip
  gemm_bt<<<dim3(16, 16, 4), 256, 0, stream>>>(
      q, kk, (void*)sc, flag, 2048, 2048, 1024, (long)SEQ * DIM,
      (long)SEQ * DIM, (long)SEQ * SEQ, 0, 1.0f, 1.0f, 1, 0, 1, 1);

  // causal softmax: bf16 logits -> bf16 P
  softmax_p<<<dim3(4 * SEQ), 256, 0, stream>>>(sc, p);

  // out = P @ V^T; balanced causal swizzle + causal K-limit
  gemm_bt<<<dim3(8, 16, 4), 256, 0, stream>>>(
      p, vt, d_out, flag, 2048, 1024, 2048, (long)SEQ * SEQ, (long)DIM * SEQ,
      (long)SEQ * DIM, 0, 1.0f, 1.0f, 0, 1, 1, 2);
}

// Round 7
// 265.636 us; speedup vs baseline: 1.1862x; 1.0366x over previous
//
#include <hip/hip_runtime.h>

#define SEQ 2048
#define DIM 1024

typedef __attribute__((ext_vector_type(8))) __bf16 bf16x8;
typedef __attribute__((ext_vector_type(4))) float f32x4;

typedef __attribute__((address_space(1))) unsigned char gu8_t;
typedef __attribute__((address_space(3))) unsigned char lu8_t;

__device__ __forceinline__ void async_copy16(const void* g, void* l) {
  __builtin_amdgcn_global_load_lds((gu8_t*)g, (lu8_t*)l, 16, 0, 0);
}

__device__ __forceinline__ ushort f2bf(float f) {
  union { float f; unsigned u; } v;
  v.f = f;
  unsigned r = v.u + 0x7FFFu + ((v.u >> 16) & 1u);
  return (ushort)(r >> 16);
}

__global__ void detect_dtype(const unsigned* __restrict__ words,
                             int* __restrict__ flag) {
  const int t = threadIdx.x;
  int hits = 0;
  for (int i = 0; i < 64; i++) {
    const unsigned w = words[t * 64 + i];
    const unsigned b = (w >> 8) & 0x7Fu;
    hits += (b >= 0x3Bu && b <= 0x42u) ? 1 : 0;
  }
#pragma unroll
  for (int o = 32; o > 0; o >>= 1) hits += __shfl_xor(hits, o, 64);
  if (t == 0) *flag = (hits > 2048) ? 1 : 0;
}

__global__ void convert_x(const void* __restrict__ in,
                          ushort* __restrict__ out,
                          const int* __restrict__ flag, int n8) {
  const int i = blockIdx.x * 256 + threadIdx.x;
  if (i >= n8) return;
  if (*flag) {
    reinterpret_cast<uint4*>(out)[i] = reinterpret_cast<const uint4*>(in)[i];
  } else {
    const float4* f = reinterpret_cast<const float4*>(in);
    const float4 a = f[2 * i], b = f[2 * i + 1];
    ushort4 lo, hi;
    lo.x = f2bf(a.x); lo.y = f2bf(a.y); lo.z = f2bf(a.z); lo.w = f2bf(a.w);
    hi.x = f2bf(b.x); hi.y = f2bf(b.y); hi.z = f2bf(b.z); hi.w = f2bf(b.w);
    reinterpret_cast<ushort4*>(out)[2 * i] = lo;
    reinterpret_cast<ushort4*>(out)[2 * i + 1] = hi;
  }
}

__global__ void transpose_w(const void* __restrict__ w0,
                            const void* __restrict__ w1,
                            const void* __restrict__ w2,
                            ushort* __restrict__ out,
                            const int* __restrict__ flag) {
  __shared__ ushort tile[64][68];
  const int z = blockIdx.z;
  const void* in = (z == 0) ? w0 : (z == 1) ? w1 : w2;
  ushort* op = out + (size_t)z * 1024 * 1024;
  const int c0 = blockIdx.x * 64, r0 = blockIdx.y * 64;
  const int t = threadIdx.x;
  if (*flag) {
    const ushort* ip = (const ushort*)in;
#pragma unroll
    for (int i = 0; i < 4; i++) {
      const int lin = i * 256 + t;
      const int r = lin >> 4, c4 = (lin & 15) << 2;
      const ushort4 v = *reinterpret_cast<const ushort4*>(
          ip + (size_t)(r0 + r) * 1024 + c0 + c4);
      tile[r][c4 + 0] = v.x; tile[r][c4 + 1] = v.y;
      tile[r][c4 + 2] = v.z; tile[r][c4 + 3] = v.w;
    }
  } else {
    const float* ip = (const float*)in;
#pragma unroll
    for (int i = 0; i < 4; i++) {
      const int lin = i * 256 + t;
      const int r = lin >> 4, c4 = (lin & 15) << 2;
      const float4 v = *reinterpret_cast<const float4*>(
          ip + (size_t)(r0 + r) * 1024 + c0 + c4);
      tile[r][c4 + 0] = f2bf(v.x); tile[r][c4 + 1] = f2bf(v.y);
      tile[r][c4 + 2] = f2bf(v.z); tile[r][c4 + 3] = f2bf(v.w);
    }
  }
  __syncthreads();
#pragma unroll
  for (int i = 0; i < 4; i++) {
    const int lin = i * 256 + t;
    const int c = lin >> 4, r4 = (lin & 15) << 2;
    ushort4 v;
    v.x = tile[r4 + 0][c]; v.y = tile[r4 + 1][c];
    v.z = tile[r4 + 2][c]; v.w = tile[r4 + 3][c];
    *reinterpret_cast<ushort4*>(op + (size_t)(c0 + c) * 1024 + r0 + r4) = v;
  }
}

__global__ void transpose_bf16(const ushort* __restrict__ in,
                               ushort* __restrict__ out, int R, int C,
                               long inZ, long outZ) {
  __shared__ ushort tile[64][68];
  const ushort* ip = in + (size_t)blockIdx.z * inZ;
  ushort* op = out + (size_t)blockIdx.z * outZ;
  const int c0 = blockIdx.x * 64, r0 = blockIdx.y * 64;
  const int t = threadIdx.x;
#pragma unroll
  for (int i = 0; i < 4; i++) {
    const int lin = i * 256 + t;
    const int r = lin >> 4, c4 = (lin & 15) << 2;
    const ushort4 v =
        *reinterpret_cast<const ushort4*>(ip + (size_t)(r0 + r) * C + c0 + c4);
    tile[r][c4 + 0] = v.x; tile[r][c4 + 1] = v.y;
    tile[r][c4 + 2] = v.z; tile[r][c4 + 3] = v.w;
  }
  __syncthreads();
#pragma unroll
  for (int i = 0; i < 4; i++) {
    const int lin = i * 256 + t;
    const int c = lin >> 4, r4 = (lin & 15) << 2;
    ushort4 v;
    v.x = tile[r4 + 0][c]; v.y = tile[r4 + 1][c];
    v.z = tile[r4 + 2][c]; v.w = tile[r4 + 3][c];
    *reinterpret_cast<ushort4*>(op + (size_t)(c0 + c) * R + r0 + r4) = v;
  }
}

// XCD-aware swizzle GEMM (r4: FETCH 135->41MB). C=A*Bt^T, 128x128 tile.
// causalBal=1 (needs gridDim.y==16): XCD owns m-tile pair {xcd, 15-xcd}.
// epi: 0 = scale+store (outKind 0 fp32 / 1 bf16 / 2 by flag)
//      1 = scores: E=exp(S) causal-masked, bf16 store + per-row sum atomics
//      2 = PV: scale rows by 1/lsum (preloaded reciprocal), store by flag
__global__ __launch_bounds__(256, 4) void gemm_bt(
    const ushort* __restrict__ A, const ushort* __restrict__ Bt,
    void* __restrict__ Cv, const int* __restrict__ flag,
    float* __restrict__ lsum, int M, int N, int K, long aZ, long bZ, long cZ,
    int zBase, float scale0, float scale1, int triSkip, int causalK,
    int causalBal, int epi, int outKind) {
  __shared__ ushort lA[128 * 32];
  __shared__ ushort lB[128 * 32];
  __shared__ float lsh[128];

  const int nT = gridDim.x;
  const int id = blockIdx.y * nT + blockIdx.x;
  const int xcd = id & 7;
  const int loc = id >> 3;
  const int nt = loc % nT;
  const int mt = causalBal
                     ? ((loc / nT == 0) ? xcd : ((int)gridDim.y - 1 - xcd))
                     : (xcd + ((loc / nT) << 3));
  const int n0 = nt * 128;
  const int m0 = mt * 128;
  if (triSkip && n0 > m0 + 127) return;

  const int zAbs = zBase + blockIdx.z;
  const ushort* Ab = A + (size_t)blockIdx.z * aZ;
  const ushort* Bb = Bt + (size_t)blockIdx.z * bZ;

  const int t = threadIdx.x;
  const int lane = t & 63;
  const int w = t >> 6;
  const int wm = (w >> 1) * 64;
  const int wn = (w & 1) * 64;
  const int quad = lane >> 4;
  const int l15 = lane & 15;

  if (epi == 2 && t < 128)
    lsh[t] = 1.0f / lsum[(size_t)zAbs * M + m0 + t];

  f32x4 acc[4][4] = {};

  const int kEnd = causalK ? ((m0 + 128 < K) ? (m0 + 128) : K) : K;

  const int idx0 = t;
  const int idx1 = t + 256;
  const int rowA0 = idx0 >> 2, colA0 = (idx0 & 3) << 3;
  const int rowA1 = idx1 >> 2, colA1 = (idx1 & 3) << 3;

  for (int k0 = 0; k0 < kEnd; k0 += 32) {
    __syncthreads();  // also makes lsh visible for the epilogue
    async_copy16(Ab + (size_t)(m0 + rowA0) * K + k0 + colA0, lA + idx0 * 8);
    async_copy16(Ab + (size_t)(m0 + rowA1) * K + k0 + colA1, lA + idx1 * 8);
    async_copy16(Bb + (size_t)(n0 + rowA0) * K + k0 + colA0, lB + idx0 * 8);
    async_copy16(Bb + (size_t)(n0 + rowA1) * K + k0 + colA1, lB + idx1 * 8);
    __syncthreads();

    bf16x8 af[4], bfr[4];
#pragma unroll
    for (int mi = 0; mi < 4; mi++)
      af[mi] = *(const bf16x8*)(lA + (wm + mi * 16 + l15) * 32 + quad * 8);
#pragma unroll
    for (int ni = 0; ni < 4; ni++)
      bfr[ni] = *(const bf16x8*)(lB + (wn + ni * 16 + l15) * 32 + quad * 8);
#pragma unroll
    for (int mi = 0; mi < 4; mi++)
#pragma unroll
      for (int ni = 0; ni < 4; ni++)
        acc[mi][ni] = __builtin_amdgcn_mfma_f32_16x16x32_bf16(
            af[mi], bfr[ni], acc[mi][ni], 0, 0, 0);
  }

  const size_t zc = (size_t)zAbs * cZ;

  if (epi == 1) {
    // E = exp(S) with causal mask; bf16 store; per-row sums via one
    // atomicAdd per 16-lane group. Layout: col=lane&15, row=quad*4+r.
    ushort* C = (ushort*)Cv + zc;
    float* ls = lsum + (size_t)zAbs * M;
#pragma unroll
    for (int mi = 0; mi < 4; mi++)
#pragma unroll
      for (int r = 0; r < 4; r++) {
        const int row = m0 + wm + mi * 16 + quad * 4 + r;
        float partial = 0.0f;
#pragma unroll
        for (int ni = 0; ni < 4; ni++) {
          const int col = n0 + wn + ni * 16 + l15;
          const float ev = (col <= row) ? __expf(acc[mi][ni][r]) : 0.0f;
          C[(size_t)row * N + col] = f2bf(ev);
          partial += ev;
        }
#pragma unroll
        for (int o = 1; o < 16; o <<= 1)
          partial += __shfl_xor(partial, o, 64);
        if (l15 == 0) atomicAdd(&ls[row], partial);
      }
    return;
  }

  const float scale = (blockIdx.z == 0 && zBase == 0) ? scale0 : scale1;
  const bool storeBf = (outKind == 1) || (outKind == 2 && *flag != 0);
#pragma unroll
  for (int mi = 0; mi < 4; mi++)
#pragma unroll
    for (int ni = 0; ni < 4; ni++)
#pragma unroll
      for (int r = 0; r < 4; r++) {
        const int lrow = wm + mi * 16 + quad * 4 + r;
        const int row = m0 + lrow;
        const int col = n0 + wn + ni * 16 + l15;
        const float sc = (epi == 2) ? lsh[lrow] : scale;
        const float vv = acc[mi][ni][r] * sc;
        if (storeBf) {
          ushort* C = (ushort*)Cv + zc;
          C[(size_t)row * N + col] = f2bf(vv);
        } else {
          float* C = (float*)Cv + zc;
          C[(size_t)row * N + col] = vv;
        }
      }
}

// Workspace (MB): 0 flag | 1 wt(6) | 7 xb(16) | 23 q | 39 k | 55 v |
// 71 vt(16) | 87 sc=E bf16(32) | 119 lsum (32KB)
extern "C" void kernel_launch(void* const* d_in, const int* in_sizes, int n_in,
                              void* d_out, int out_size, void* d_ws,
                              size_t ws_size, hipStream_t stream) {
  char* ws = (char*)d_ws;
  const size_t MB = 1024 * 1024;
  int* flag = (int*)ws;
  ushort* wt = (ushort*)(ws + 1 * MB);
  ushort* xb = (ushort*)(ws + 7 * MB);
  ushort* q = (ushort*)(ws + 23 * MB);
  ushort* kk = (ushort*)(ws + 39 * MB);
  ushort* v = (ushort*)(ws + 55 * MB);
  ushort* vt = (ushort*)(ws + 71 * MB);
  ushort* sc = (ushort*)(ws + 87 * MB);
  float* lsum = (float*)(ws + 119 * MB);
  (void)kk;

  detect_dtype<<<dim3(1), 64, 0, stream>>>((const unsigned*)d_in[0], flag);

  // zero the row-sum accumulator (workspace is poisoned each launch)
  hipMemsetAsync(lsum, 0, 4 * SEQ * sizeof(float), stream);

  convert_x<<<dim3(4096), 256, 0, stream>>>(d_in[0], xb, flag,
                                            (8192 * 1024) / 8);

  transpose_w<<<dim3(16, 16, 3), 256, 0, stream>>>(d_in[1], d_in[2], d_in[3],
                                                   wt, flag);

  // QKV projections: z=0 -> Q (scaled 1/sqrt(1024)=1/32), z=1 -> K, z=2 -> V
  gemm_bt<<<dim3(8, 64, 3), 256, 0, stream>>>(
      xb, wt, (void*)q, flag, nullptr, 8192, 1024, 1024, 0L,
      (long)1024 * 1024, (long)8192 * 1024, 0, 0.03125f, 1.0f, 0, 0, 0, 0, 1);

  transpose_bf16<<<dim3(16, 32, 4), 256, 0, stream>>>(
      v, vt, 2048, 1024, (long)SEQ * DIM, (long)DIM * SEQ);

  // E = exp(Q*K^T) (causal-masked) -> bf16, + per-row sums l
  gemm_bt<<<dim3(16, 16, 4), 256, 0, stream>>>(
      q, kk, (void*)sc, flag, lsum, 2048, 2048, 1024, (long)SEQ * DIM,
      (long)SEQ * DIM, (long)SEQ * SEQ, 0, 1.0f, 1.0f, 1, 0, 1, 1, 1);

  // out = diag(1/l) * (E @ V^T); balanced causal swizzle + causal K-limit
  gemm_bt<<<dim3(8, 16, 4), 256, 0, stream>>>(
      sc, vt, d_out, flag, lsum, 2048, 1024, 2048, (long)SEQ * SEQ,
      (long)DIM * SEQ, (long)SEQ * DIM, 0, 1.0f, 1.0f, 0, 1, 1, 2, 2);
}

// Round 8
// 260.225 us; speedup vs baseline: 1.2109x; 1.0208x over previous
//
#include <hip/hip_runtime.h>

#define SEQ 2048
#define DIM 1024

typedef __attribute__((ext_vector_type(8))) __bf16 bf16x8;
typedef __attribute__((ext_vector_type(4))) float f32x4;

typedef __attribute__((address_space(1))) unsigned char gu8_t;
typedef __attribute__((address_space(3))) unsigned char lu8_t;

__device__ __forceinline__ void async_copy16(const void* g, void* l) {
  __builtin_amdgcn_global_load_lds((gu8_t*)g, (lu8_t*)l, 16, 0, 0);
}

__device__ __forceinline__ ushort f2bf(float f) {
  union { float f; unsigned u; } v;
  v.f = f;
  unsigned r = v.u + 0x7FFFu + ((v.u >> 16) & 1u);
  return (ushort)(r >> 16);
}

__global__ void detect_dtype(const unsigned* __restrict__ words,
                             int* __restrict__ flag) {
  const int t = threadIdx.x;
  int hits = 0;
  for (int i = 0; i < 64; i++) {
    const unsigned w = words[t * 64 + i];
    const unsigned b = (w >> 8) & 0x7Fu;
    hits += (b >= 0x3Bu && b <= 0x42u) ? 1 : 0;
  }
#pragma unroll
  for (int o = 32; o > 0; o >>= 1) hits += __shfl_xor(hits, o, 64);
  if (t == 0) *flag = (hits > 2048) ? 1 : 0;
}

__global__ void convert_x(const void* __restrict__ in,
                          ushort* __restrict__ out,
                          const int* __restrict__ flag, int n8) {
  const int i = blockIdx.x * 256 + threadIdx.x;
  if (i >= n8) return;
  if (*flag) {
    reinterpret_cast<uint4*>(out)[i] = reinterpret_cast<const uint4*>(in)[i];
  } else {
    const float4* f = reinterpret_cast<const float4*>(in);
    const float4 a = f[2 * i], b = f[2 * i + 1];
    ushort4 lo, hi;
    lo.x = f2bf(a.x); lo.y = f2bf(a.y); lo.z = f2bf(a.z); lo.w = f2bf(a.w);
    hi.x = f2bf(b.x); hi.y = f2bf(b.y); hi.z = f2bf(b.z); hi.w = f2bf(b.w);
    reinterpret_cast<ushort4*>(out)[2 * i] = lo;
    reinterpret_cast<ushort4*>(out)[2 * i + 1] = hi;
  }
}

__global__ void transpose_w(const void* __restrict__ w0,
                            const void* __restrict__ w1,
                            const void* __restrict__ w2,
                            ushort* __restrict__ out,
                            const int* __restrict__ flag) {
  __shared__ ushort tile[64][68];
  const int z = blockIdx.z;
  const void* in = (z == 0) ? w0 : (z == 1) ? w1 : w2;
  ushort* op = out + (size_t)z * 1024 * 1024;
  const int c0 = blockIdx.x * 64, r0 = blockIdx.y * 64;
  const int t = threadIdx.x;
  if (*flag) {
    const ushort* ip = (const ushort*)in;
#pragma unroll
    for (int i = 0; i < 4; i++) {
      const int lin = i * 256 + t;
      const int r = lin >> 4, c4 = (lin & 15) << 2;
      const ushort4 v = *reinterpret_cast<const ushort4*>(
          ip + (size_t)(r0 + r) * 1024 + c0 + c4);
      tile[r][c4 + 0] = v.x; tile[r][c4 + 1] = v.y;
      tile[r][c4 + 2] = v.z; tile[r][c4 + 3] = v.w;
    }
  } else {
    const float* ip = (const float*)in;
#pragma unroll
    for (int i = 0; i < 4; i++) {
      const int lin = i * 256 + t;
      const int r = lin >> 4, c4 = (lin & 15) << 2;
      const float4 v = *reinterpret_cast<const float4*>(
          ip + (size_t)(r0 + r) * 1024 + c0 + c4);
      tile[r][c4 + 0] = f2bf(v.x); tile[r][c4 + 1] = f2bf(v.y);
      tile[r][c4 + 2] = f2bf(v.z); tile[r][c4 + 3] = f2bf(v.w);
    }
  }
  __syncthreads();
#pragma unroll
  for (int i = 0; i < 4; i++) {
    const int lin = i * 256 + t;
    const int c = lin >> 4, r4 = (lin & 15) << 2;
    ushort4 v;
    v.x = tile[r4 + 0][c]; v.y = tile[r4 + 1][c];
    v.z = tile[r4 + 2][c]; v.w = tile[r4 + 3][c];
    *reinterpret_cast<ushort4*>(op + (size_t)(c0 + c) * 1024 + r0 + r4) = v;
  }
}

__global__ void transpose_bf16(const ushort* __restrict__ in,
                               ushort* __restrict__ out, int R, int C,
                               long inZ, long outZ) {
  __shared__ ushort tile[64][68];
  const ushort* ip = in + (size_t)blockIdx.z * inZ;
  ushort* op = out + (size_t)blockIdx.z * outZ;
  const int c0 = blockIdx.x * 64, r0 = blockIdx.y * 64;
  const int t = threadIdx.x;
#pragma unroll
  for (int i = 0; i < 4; i++) {
    const int lin = i * 256 + t;
    const int r = lin >> 4, c4 = (lin & 15) << 2;
    const ushort4 v =
        *reinterpret_cast<const ushort4*>(ip + (size_t)(r0 + r) * C + c0 + c4);
    tile[r][c4 + 0] = v.x; tile[r][c4 + 1] = v.y;
    tile[r][c4 + 2] = v.z; tile[r][c4 + 3] = v.w;
  }
  __syncthreads();
#pragma unroll
  for (int i = 0; i < 4; i++) {
    const int lin = i * 256 + t;
    const int c = lin >> 4, r4 = (lin & 15) << 2;
    ushort4 v;
    v.x = tile[r4 + 0][c]; v.y = tile[r4 + 1][c];
    v.z = tile[r4 + 2][c]; v.w = tile[r4 + 3][c];
    *reinterpret_cast<ushort4*>(op + (size_t)(c0 + c) * R + r0 + r4) = v;
  }
}

// Fully-specialized XCD-swizzled 128x128 GEMM: C = A * Bt^T.
// EPI 0: scale+store | 1: E=exp(S) masked + row-sum atomics | 2: 1/l scaling.
// OUTK 0: fp32 | 1: bf16 | 2: by *flag. CBAL: balanced causal m-tile pairs.
// All shapes/strides compile-time for clean K-loop codegen.
template <int EPI, int OUTK, int TRI, int CK, int CBAL, int M, int N, int K,
          long AZ, long BZ, long CZ>
__global__ __launch_bounds__(256, 4) void gemm_t(
    const ushort* __restrict__ A, const ushort* __restrict__ Bt,
    void* __restrict__ Cv, const int* __restrict__ flag,
    float* __restrict__ lsum, float scale0, float scale1) {
  __shared__ ushort lA[128 * 32];
  __shared__ ushort lB[128 * 32];
  __shared__ float lsh[(EPI == 2) ? 128 : 1];

  constexpr int MT = M / 128;
  const int nT = gridDim.x;
  const int id = blockIdx.y * nT + blockIdx.x;
  const int xcd = id & 7;
  const int loc = id >> 3;
  const int nt = loc % nT;
  const int mt = CBAL ? ((loc / nT == 0) ? xcd : (MT - 1 - xcd))
                      : (xcd + ((loc / nT) << 3));
  const int n0 = nt * 128;
  const int m0 = mt * 128;
  if (TRI && n0 > m0 + 127) return;

  const int z = blockIdx.z;
  const ushort* Ab = A + (size_t)z * AZ;
  const ushort* Bb = Bt + (size_t)z * BZ;

  const int t = threadIdx.x;
  const int lane = t & 63;
  const int w = t >> 6;
  const int wm = (w >> 1) * 64;
  const int wn = (w & 1) * 64;
  const int quad = lane >> 4;
  const int l15 = lane & 15;

  if constexpr (EPI == 2) {
    if (t < 128) lsh[t] = 1.0f / lsum[(size_t)z * M + m0 + t];
  }

  f32x4 acc[4][4] = {};

  const int kEnd = CK ? ((m0 + 128 < K) ? (m0 + 128) : K) : K;

  const int idx0 = t;
  const int idx1 = t + 256;
  const int rowA0 = idx0 >> 2, colA0 = (idx0 & 3) << 3;
  const int rowA1 = idx1 >> 2, colA1 = (idx1 & 3) << 3;

  for (int k0 = 0; k0 < kEnd; k0 += 32) {
    __syncthreads();
    async_copy16(Ab + (size_t)(m0 + rowA0) * K + k0 + colA0, lA + idx0 * 8);
    async_copy16(Ab + (size_t)(m0 + rowA1) * K + k0 + colA1, lA + idx1 * 8);
    async_copy16(Bb + (size_t)(n0 + rowA0) * K + k0 + colA0, lB + idx0 * 8);
    async_copy16(Bb + (size_t)(n0 + rowA1) * K + k0 + colA1, lB + idx1 * 8);
    __syncthreads();

    bf16x8 af[4], bfr[4];
#pragma unroll
    for (int mi = 0; mi < 4; mi++)
      af[mi] = *(const bf16x8*)(lA + (wm + mi * 16 + l15) * 32 + quad * 8);
#pragma unroll
    for (int ni = 0; ni < 4; ni++)
      bfr[ni] = *(const bf16x8*)(lB + (wn + ni * 16 + l15) * 32 + quad * 8);
#pragma unroll
    for (int mi = 0; mi < 4; mi++)
#pragma unroll
      for (int ni = 0; ni < 4; ni++)
        acc[mi][ni] = __builtin_amdgcn_mfma_f32_16x16x32_bf16(
            af[mi], bfr[ni], acc[mi][ni], 0, 0, 0);
  }

  const size_t zc = (size_t)z * CZ;

  if constexpr (EPI == 1) {
    // E = exp(S), causal mask; bf16 store; one atomicAdd per row per block.
    ushort* C = (ushort*)Cv + zc;
    float* ls = lsum + (size_t)z * M;
#pragma unroll
    for (int mi = 0; mi < 4; mi++)
#pragma unroll
      for (int r = 0; r < 4; r++) {
        const int row = m0 + wm + mi * 16 + quad * 4 + r;
        float partial = 0.0f;
#pragma unroll
        for (int ni = 0; ni < 4; ni++) {
          const int col = n0 + wn + ni * 16 + l15;
          const float ev = (col <= row) ? __expf(acc[mi][ni][r]) : 0.0f;
          C[(size_t)row * N + col] = f2bf(ev);
          partial += ev;
        }
#pragma unroll
        for (int o = 1; o < 16; o <<= 1) partial += __shfl_xor(partial, o, 64);
        if (l15 == 0) atomicAdd(&ls[row], partial);
      }
    return;
  } else {
    const float scale = (z == 0) ? scale0 : scale1;
    const bool storeBf = (OUTK == 1) || (OUTK == 2 && *flag != 0);
#pragma unroll
    for (int mi = 0; mi < 4; mi++)
#pragma unroll
      for (int ni = 0; ni < 4; ni++)
#pragma unroll
        for (int r = 0; r < 4; r++) {
          const int lrow = wm + mi * 16 + quad * 4 + r;
          const int row = m0 + lrow;
          const int col = n0 + wn + ni * 16 + l15;
          const float sc = (EPI == 2) ? lsh[lrow] : scale;
          const float vv = acc[mi][ni][r] * sc;
          if (storeBf) {
            ushort* C = (ushort*)Cv + zc;
            C[(size_t)row * N + col] = f2bf(vv);
          } else {
            float* C = (float*)Cv + zc;
            C[(size_t)row * N + col] = vv;
          }
        }
  }
}

// Instantiations:
// proj:   M=8192 N=1024 K=1024, AZ=0, BZ=1024*1024, CZ=8192*1024, bf16 out
// scores: M=2048 N=2048 K=1024, AZ/BZ=SEQ*DIM, CZ=SEQ*SEQ, EPI=1, TRI, CBAL
// pv:     M=2048 N=1024 K=2048, AZ=SEQ*SEQ, BZ=DIM*SEQ, CZ=SEQ*DIM, EPI=2
using ProjT = void (*)(const ushort*, const ushort*, void*, const int*,
                       float*, float, float);

// Workspace (MB): 0 flag | 1 wt(6) | 7 xb(16) | 23 q | 39 k | 55 v |
// 71 vt(16) | 87 E bf16(32) | 119 lsum(32KB)
extern "C" void kernel_launch(void* const* d_in, const int* in_sizes, int n_in,
                              void* d_out, int out_size, void* d_ws,
                              size_t ws_size, hipStream_t stream) {
  char* ws = (char*)d_ws;
  const size_t MB = 1024 * 1024;
  int* flag = (int*)ws;
  ushort* wt = (ushort*)(ws + 1 * MB);
  ushort* xb = (ushort*)(ws + 7 * MB);
  ushort* q = (ushort*)(ws + 23 * MB);
  ushort* kk = (ushort*)(ws + 39 * MB);
  ushort* v = (ushort*)(ws + 55 * MB);
  ushort* vt = (ushort*)(ws + 71 * MB);
  ushort* sc = (ushort*)(ws + 87 * MB);
  float* lsum = (float*)(ws + 119 * MB);
  (void)kk;

  detect_dtype<<<dim3(1), 64, 0, stream>>>((const unsigned*)d_in[0], flag);

  hipMemsetAsync(lsum, 0, 4 * SEQ * sizeof(float), stream);

  convert_x<<<dim3(4096), 256, 0, stream>>>(d_in[0], xb, flag,
                                            (8192 * 1024) / 8);

  transpose_w<<<dim3(16, 16, 3), 256, 0, stream>>>(d_in[1], d_in[2], d_in[3],
                                                   wt, flag);

  // QKV projections: z=0 -> Q (scaled 1/32), z=1 -> K, z=2 -> V
  gemm_t<0, 1, 0, 0, 0, 8192, 1024, 1024, 0L, 1024L * 1024, 8192L * 1024>
      <<<dim3(8, 64, 3), 256, 0, stream>>>(xb, wt, (void*)q, flag, nullptr,
                                           0.03125f, 1.0f);

  transpose_bf16<<<dim3(16, 32, 4), 256, 0, stream>>>(
      v, vt, 2048, 1024, (long)SEQ * DIM, (long)DIM * SEQ);

  // E = exp(Q*K^T) causal-masked -> bf16, + per-row sums
  gemm_t<1, 1, 1, 0, 1, 2048, 2048, 1024, (long)SEQ * DIM, (long)SEQ * DIM,
         (long)SEQ * SEQ>
      <<<dim3(16, 16, 4), 256, 0, stream>>>(q, kk, (void*)sc, flag, lsum,
                                            1.0f, 1.0f);

  // out = diag(1/l) * (E @ V^T)
  gemm_t<2, 2, 0, 1, 1, 2048, 1024, 2048, (long)SEQ * SEQ, (long)DIM * SEQ,
         (long)SEQ * DIM>
      <<<dim3(8, 16, 4), 256, 0, stream>>>(sc, vt, d_out, flag, lsum, 1.0f,
                                           1.0f);
}

// Round 9
// 256.982 us; speedup vs baseline: 1.2262x; 1.0126x over previous
//
#include <hip/hip_runtime.h>

#define SEQ 2048
#define DIM 1024

typedef __attribute__((ext_vector_type(8))) __bf16 bf16x8;
typedef __attribute__((ext_vector_type(4))) float f32x4;

typedef __attribute__((address_space(1))) unsigned char gu8_t;
typedef __attribute__((address_space(3))) unsigned char lu8_t;

__device__ __forceinline__ void async_copy16(const void* g, void* l) {
  __builtin_amdgcn_global_load_lds((gu8_t*)g, (lu8_t*)l, 16, 0, 0);
}

__device__ __forceinline__ ushort f2bf(float f) {
  union { float f; unsigned u; } v;
  v.f = f;
  unsigned r = v.u + 0x7FFFu + ((v.u >> 16) & 1u);
  return (ushort)(r >> 16);
}

// Detect input packing (bf16 vs fp32) from x, and zero the lsum accumulator.
__global__ void detect_and_zero(const unsigned* __restrict__ words,
                                int* __restrict__ flag,
                                float* __restrict__ lsum) {
  const int t = threadIdx.x;
  // zero 4*SEQ floats of lsum
  for (int i = t; i < 4 * SEQ; i += 256) lsum[i] = 0.0f;
  if (t < 64) {
    int hits = 0;
    for (int i = 0; i < 64; i++) {
      const unsigned w = words[t * 64 + i];
      const unsigned b = (w >> 8) & 0x7Fu;
      hits += (b >= 0x3Bu && b <= 0x42u) ? 1 : 0;
    }
#pragma unroll
    for (int o = 32; o > 0; o >>= 1) hits += __shfl_xor(hits, o, 64);
    if (t == 0) *flag = (hits > 2048) ? 1 : 0;
  }
}

// Merged prep: blocks [0,4096) convert x -> bf16; blocks [4096,4864)
// transpose the three weight matrices (z = (bid-4096)>>8).
__global__ void prep(const void* __restrict__ xin, const void* __restrict__ w0,
                     const void* __restrict__ w1, const void* __restrict__ w2,
                     ushort* __restrict__ xb, ushort* __restrict__ wt,
                     const int* __restrict__ flag) {
  __shared__ ushort tile[64][68];
  const int bid = blockIdx.x;
  const int t = threadIdx.x;
  const int bf = *flag;

  if (bid < 4096) {
    const int i = bid * 256 + t;  // 8-element group index
    if (bf) {
      reinterpret_cast<uint4*>(xb)[i] =
          reinterpret_cast<const uint4*>(xin)[i];
    } else {
      const float4* f = reinterpret_cast<const float4*>(xin);
      const float4 a = f[2 * i], b = f[2 * i + 1];
      ushort4 lo, hi;
      lo.x = f2bf(a.x); lo.y = f2bf(a.y); lo.z = f2bf(a.z); lo.w = f2bf(a.w);
      hi.x = f2bf(b.x); hi.y = f2bf(b.y); hi.z = f2bf(b.z); hi.w = f2bf(b.w);
      reinterpret_cast<ushort4*>(xb)[2 * i] = lo;
      reinterpret_cast<ushort4*>(xb)[2 * i + 1] = hi;
    }
    return;
  }

  const int rem = bid - 4096;
  const int z = rem >> 8;
  const int within = rem & 255;
  const int c0 = (within & 15) * 64, r0 = (within >> 4) * 64;
  const void* in = (z == 0) ? w0 : (z == 1) ? w1 : w2;
  ushort* op = wt + (size_t)z * 1024 * 1024;

  if (bf) {
    const ushort* ip = (const ushort*)in;
#pragma unroll
    for (int i = 0; i < 4; i++) {
      const int lin = i * 256 + t;
      const int r = lin >> 4, c4 = (lin & 15) << 2;
      const ushort4 v = *reinterpret_cast<const ushort4*>(
          ip + (size_t)(r0 + r) * 1024 + c0 + c4);
      tile[r][c4 + 0] = v.x; tile[r][c4 + 1] = v.y;
      tile[r][c4 + 2] = v.z; tile[r][c4 + 3] = v.w;
    }
  } else {
    const float* ip = (const float*)in;
#pragma unroll
    for (int i = 0; i < 4; i++) {
      const int lin = i * 256 + t;
      const int r = lin >> 4, c4 = (lin & 15) << 2;
      const float4 v = *reinterpret_cast<const float4*>(
          ip + (size_t)(r0 + r) * 1024 + c0 + c4);
      tile[r][c4 + 0] = f2bf(v.x); tile[r][c4 + 1] = f2bf(v.y);
      tile[r][c4 + 2] = f2bf(v.z); tile[r][c4 + 3] = f2bf(v.w);
    }
  }
  __syncthreads();
#pragma unroll
  for (int i = 0; i < 4; i++) {
    const int lin = i * 256 + t;
    const int c = lin >> 4, r4 = (lin & 15) << 2;
    ushort4 v;
    v.x = tile[r4 + 0][c]; v.y = tile[r4 + 1][c];
    v.z = tile[r4 + 2][c]; v.w = tile[r4 + 3][c];
    *reinterpret_cast<ushort4*>(op + (size_t)(c0 + c) * 1024 + r0 + r4) = v;
  }
}

// Fully-specialized XCD-swizzled 128x128 GEMM: C[M,N] = A[M,K] * Bt[N,:]^T.
// B row stride BRS (= K normally; 8192 for PV reading Vt_all slices).
// SWIZ 0: XCD owns m-stripe (or CBAL m-pairs). SWIZ 1: XCD owns n-group.
// EPI 0: scale+store | 1: E=exp(S) masked + row-sum atomics | 2: 1/l rows.
// OUTK 0: fp32 | 1: bf16 | 2: by *flag.
template <int EPI, int OUTK, int TRI, int CK, int CBAL, int SWIZ, int M,
          int N, int K, long AZ, long BZ, long CZ, long BRS>
__global__ __launch_bounds__(256, 4) void gemm_t(
    const ushort* __restrict__ A, const ushort* __restrict__ Bt,
    void* __restrict__ Cv, const int* __restrict__ flag,
    float* __restrict__ lsum, float scale0, float scale1) {
  __shared__ ushort lA[128 * 32];
  __shared__ ushort lB[128 * 32];
  __shared__ float lsh[(EPI == 2) ? 128 : 1];

  constexpr int MT = M / 128;
  const int nT = gridDim.x;
  const int id = blockIdx.y * nT + blockIdx.x;
  const int xcd = id & 7;
  const int loc = id >> 3;
  int nt, mt;
  if constexpr (SWIZ == 1) {
    const int ng = nT >> 3;  // n-tiles per XCD
    nt = xcd * ng + loc % ng;
    mt = loc / ng;
  } else {
    nt = loc % nT;
    mt = CBAL ? ((loc / nT == 0) ? xcd : (MT - 1 - xcd))
              : (xcd + ((loc / nT) << 3));
  }
  const int n0 = nt * 128;
  const int m0 = mt * 128;
  if (TRI && n0 > m0 + 127) return;

  const int z = blockIdx.z;
  const ushort* Ab = A + (size_t)z * AZ;
  const ushort* Bb = Bt + (size_t)z * BZ;

  const int t = threadIdx.x;
  const int lane = t & 63;
  const int w = t >> 6;
  const int wm = (w >> 1) * 64;
  const int wn = (w & 1) * 64;
  const int quad = lane >> 4;
  const int l15 = lane & 15;

  if constexpr (EPI == 2) {
    if (t < 128) lsh[t] = 1.0f / lsum[(size_t)z * M + m0 + t];
  }

  f32x4 acc[4][4] = {};

  const int kEnd = CK ? ((m0 + 128 < K) ? (m0 + 128) : K) : K;

  const int idx0 = t;
  const int idx1 = t + 256;
  const int rowA0 = idx0 >> 2, colA0 = (idx0 & 3) << 3;
  const int rowA1 = idx1 >> 2, colA1 = (idx1 & 3) << 3;

  for (int k0 = 0; k0 < kEnd; k0 += 32) {
    __syncthreads();
    async_copy16(Ab + (size_t)(m0 + rowA0) * K + k0 + colA0, lA + idx0 * 8);
    async_copy16(Ab + (size_t)(m0 + rowA1) * K + k0 + colA1, lA + idx1 * 8);
    async_copy16(Bb + (size_t)(n0 + rowA0) * BRS + k0 + colA0, lB + idx0 * 8);
    async_copy16(Bb + (size_t)(n0 + rowA1) * BRS + k0 + colA1, lB + idx1 * 8);
    __syncthreads();

    bf16x8 af[4], bfr[4];
#pragma unroll
    for (int mi = 0; mi < 4; mi++)
      af[mi] = *(const bf16x8*)(lA + (wm + mi * 16 + l15) * 32 + quad * 8);
#pragma unroll
    for (int ni = 0; ni < 4; ni++)
      bfr[ni] = *(const bf16x8*)(lB + (wn + ni * 16 + l15) * 32 + quad * 8);
#pragma unroll
    for (int mi = 0; mi < 4; mi++)
#pragma unroll
      for (int ni = 0; ni < 4; ni++)
        acc[mi][ni] = __builtin_amdgcn_mfma_f32_16x16x32_bf16(
            af[mi], bfr[ni], acc[mi][ni], 0, 0, 0);
  }

  const size_t zc = (size_t)z * CZ;

  if constexpr (EPI == 1) {
    // E = exp(S), causal mask; bf16 store; one atomicAdd per row per block.
    ushort* C = (ushort*)Cv + zc;
    float* ls = lsum + (size_t)z * M;
#pragma unroll
    for (int mi = 0; mi < 4; mi++)
#pragma unroll
      for (int r = 0; r < 4; r++) {
        const int row = m0 + wm + mi * 16 + quad * 4 + r;
        float partial = 0.0f;
#pragma unroll
        for (int ni = 0; ni < 4; ni++) {
          const int col = n0 + wn + ni * 16 + l15;
          const float ev = (col <= row) ? __expf(acc[mi][ni][r]) : 0.0f;
          C[(size_t)row * N + col] = f2bf(ev);
          partial += ev;
        }
#pragma unroll
        for (int o = 1; o < 16; o <<= 1) partial += __shfl_xor(partial, o, 64);
        if (l15 == 0) atomicAdd(&ls[row], partial);
      }
    return;
  } else {
    const float scale = (z == 0) ? scale0 : scale1;
    const bool storeBf = (OUTK == 1) || (OUTK == 2 && *flag != 0);
#pragma unroll
    for (int mi = 0; mi < 4; mi++)
#pragma unroll
      for (int ni = 0; ni < 4; ni++)
#pragma unroll
        for (int r = 0; r < 4; r++) {
          const int lrow = wm + mi * 16 + quad * 4 + r;
          const int row = m0 + lrow;
          const int col = n0 + wn + ni * 16 + l15;
          const float sc = (EPI == 2) ? lsh[lrow] : scale;
          const float vv = acc[mi][ni][r] * sc;
          if (storeBf) {
            ushort* C = (ushort*)Cv + zc;
            C[(size_t)row * N + col] = f2bf(vv);
          } else {
            float* C = (float*)Cv + zc;
            C[(size_t)row * N + col] = vv;
          }
        }
  }
}

// Workspace (MB): 0 flag | 1 wt(6) | 7 xb(16) | 23 q(16) | 39 k(16) |
// 55 Vt_all [1024 x 8192] (16) | 71 E bf16(32) | 103 lsum(32KB)
extern "C" void kernel_launch(void* const* d_in, const int* in_sizes, int n_in,
                              void* d_out, int out_size, void* d_ws,
                              size_t ws_size, hipStream_t stream) {
  char* ws = (char*)d_ws;
  const size_t MB = 1024 * 1024;
  int* flag = (int*)ws;
  ushort* wt = (ushort*)(ws + 1 * MB);
  ushort* xb = (ushort*)(ws + 7 * MB);
  ushort* q = (ushort*)(ws + 23 * MB);
  ushort* kk = (ushort*)(ws + 39 * MB);
  ushort* vt = (ushort*)(ws + 55 * MB);
  ushort* sc = (ushort*)(ws + 71 * MB);
  float* lsum = (float*)(ws + 103 * MB);
  (void)kk;

  detect_and_zero<<<dim3(1), 256, 0, stream>>>((const unsigned*)d_in[0], flag,
                                               lsum);

  prep<<<dim3(4864), 256, 0, stream>>>(d_in[0], d_in[1], d_in[2], d_in[3], xb,
                                       wt, flag);

  // Q,K projections: z=0 -> Q (scaled 1/32), z=1 -> K
  gemm_t<0, 1, 0, 0, 0, 0, 8192, 1024, 1024, 0L, 1024L * 1024, 8192L * 1024,
         1024L>
      <<<dim3(8, 64, 2), 256, 0, stream>>>(xb, wt, (void*)q, flag, nullptr,
                                           0.03125f, 1.0f);

  // Vt = Wv^T * X^T directly: A = wtV [1024x1024], Bt = xb [8192x1024],
  // C = Vt_all [1024 x 8192]; n-striped XCD swizzle (B-group per XCD).
  gemm_t<0, 1, 0, 0, 0, 1, 1024, 8192, 1024, 0L, 0L, 0L, 1024L>
      <<<dim3(64, 8, 1), 256, 0, stream>>>(wt + 2 * 1024 * 1024, xb,
                                           (void*)vt, flag, nullptr, 1.0f,
                                           1.0f);

  // E = exp(Q*K^T) causal-masked -> bf16, + per-row sums
  gemm_t<1, 1, 1, 0, 1, 0, 2048, 2048, 1024, (long)SEQ * DIM, (long)SEQ * DIM,
         (long)SEQ * SEQ, (long)DIM>
      <<<dim3(16, 16, 4), 256, 0, stream>>>(q, kk, (void*)sc, flag, lsum,
                                            1.0f, 1.0f);

  // out = diag(1/l) * (E @ V^T); B = Vt_all batch slice, row stride 8192
  gemm_t<2, 2, 0, 1, 1, 0, 2048, 1024, 2048, (long)SEQ * SEQ, 2048L,
         (long)SEQ * DIM, 8192L>
      <<<dim3(8, 16, 4), 256, 0, stream>>>(sc, vt, d_out, flag, lsum, 1.0f,
                                           1.0f);
}